// Round 2
// baseline (394.300 us; speedup 1.0000x reference)
//
#include <hip/hip_runtime.h>

typedef unsigned int   uint32;
typedef unsigned short ushort16;

#define NN       50000
#define RR       16
#define BB       8
#define DIN      128
#define DOUT     128
#define K2       1024          // B*DIN (basis-combined K)
#define NNZ_C    1600000
#define NKEY     800000        // N*R keys for the (row,r) counting sort
#define EPB      4096          // edges per block in sort passes
#define NBLK_E   391           // ceil(NNZ/EPB)
#define NBLK_K   196           // ceil(NKEY/4096)

typedef short  short8  __attribute__((ext_vector_type(8)));
typedef float  floatx4 __attribute__((ext_vector_type(4)));
typedef float  float2v __attribute__((ext_vector_type(2)));
typedef uint32 uint2v  __attribute__((ext_vector_type(2)));

__device__ __forceinline__ ushort16 f2bf(float f) {
    uint32 u = __float_as_uint(f);
    u += 0x7fffu + ((u >> 16) & 1u);   // RNE
    return (ushort16)(u >> 16);
}

// pack two f32 -> (bf16(b)<<16)|bf16(a), round-half-up
__device__ __forceinline__ uint32 pack_bf16(float a, float b) {
    uint32 ua = __float_as_uint(a) + 0x8000u;
    uint32 ub = __float_as_uint(b) + 0x8000u;
    return __builtin_amdgcn_perm(ub, ua, 0x07060302);
}

// async global->LDS, 16B per lane; LDS dest = uniform base + lane*16
__device__ __forceinline__ void gload16(const void* g, void* l) {
    __builtin_amdgcn_global_load_lds(
        (const __attribute__((address_space(1))) uint32*)g,
        (__attribute__((address_space(3))) uint32*)l, 16, 0, 0);
}

// ---------------------------------------------------------------------------
// Bst[jout][b*128+jin] = basis[b][jin][jout]   (bf16 transpose-cast)
// ---------------------------------------------------------------------------
__global__ void build_bst_kernel(const float* __restrict__ basis,
                                 ushort16* __restrict__ Bst) {
    int idx  = blockIdx.x * 256 + threadIdx.x;   // 128*1024 = 131072
    int jout = idx >> 10;
    int bk   = idx & 1023;           // b*128 + jin
    Bst[idx] = f2bf(basis[(size_t)bk * DOUT + jout]);
}

// ---------------------------------------------------------------------------
// X (f32, N x 128) -> XD (bf16 packed dwords, N x 64 dwords)
// ---------------------------------------------------------------------------
__global__ void cvt_x_kernel(const float* __restrict__ X,
                             uint32* __restrict__ XD) {
    int d = blockIdx.x * 256 + threadIdx.x;      // 3,200,000 dwords
    float2 f = *(const float2*)(X + (size_t)d * 2);
    XD[d] = pack_bf16(f.x, f.y);
}

// ---------------------------------------------------------------------------
// Sort pass 1: histogram over 800000 (row,r) keys (global atomics, ~2/ctr)
// ---------------------------------------------------------------------------
__global__ void histK_kernel(const int* __restrict__ rows,
                             const int* __restrict__ cols,
                             int* __restrict__ cnt) {
    int tid = threadIdx.x;
    int base_e = blockIdx.x * EPB;
#pragma unroll
    for (int it = 0; it < 16; ++it) {
        int e = base_e + it * 256 + tid;
        if (e < NNZ_C) {
            int r = (int)((uint32)cols[e] / (uint32)NN);
            atomicAdd(&cnt[rows[e] * 16 + r], 1);
        }
    }
}

// ---------------------------------------------------------------------------
// Sort pass 2a: per-block exclusive scan of the 800000 counters (4096/block);
// writes block-local exclusive partials into ks, block totals into bsum.
// ---------------------------------------------------------------------------
__global__ __launch_bounds__(256) void scan1_kernel(const int* __restrict__ cnt,
                                                    int* __restrict__ ks,
                                                    int* __restrict__ bsum) {
    __shared__ int tmp[256];
    int b = blockIdx.x, tid = threadIdx.x;
    int j0 = b * 4096 + tid * 16;
    int v[16];
    int run = 0;
#pragma unroll
    for (int k = 0; k < 16; ++k) {
        int j = j0 + k;
        int c = (j < NKEY) ? cnt[j] : 0;
        v[k] = run;
        run += c;
    }
    tmp[tid] = run;
    __syncthreads();
#pragma unroll
    for (int off = 1; off < 256; off <<= 1) {
        int t = (tid >= off) ? tmp[tid - off] : 0;
        __syncthreads();
        tmp[tid] += t;
        __syncthreads();
    }
    int excl = tmp[tid] - run;
#pragma unroll
    for (int k = 0; k < 16; ++k) {
        int j = j0 + k;
        if (j < NKEY) ks[j] = v[k] + excl;
    }
    if (tid == 255) bsum[b] = tmp[255];
}

// ---------------------------------------------------------------------------
// Sort pass 2b: each block derives its global offset from bsum (block-scan of
// <=196 values), finalizes ks and seeds cursor. ks[NKEY] = NNZ.
// ---------------------------------------------------------------------------
__global__ __launch_bounds__(256) void scan2_kernel(const int* __restrict__ bsum,
                                                    int* __restrict__ ks,
                                                    int* __restrict__ cursor) {
    __shared__ int tmp[256];
    int b = blockIdx.x, tid = threadIdx.x;
    int v = (tid < b) ? bsum[tid] : 0;
    tmp[tid] = v;
    __syncthreads();
#pragma unroll
    for (int off = 1; off < 256; off <<= 1) {
        int t = (tid >= off) ? tmp[tid - off] : 0;
        __syncthreads();
        tmp[tid] += t;
        __syncthreads();
    }
    int off_b = tmp[255];       // sum of bsum[0..b)
    int j0 = b * 4096 + tid * 16;
#pragma unroll
    for (int k = 0; k < 16; ++k) {
        int j = j0 + k;
        if (j < NKEY) {
            int s = ks[j] + off_b;
            ks[j] = s;
            cursor[j] = s;
        }
    }
    if (b == 0 && tid == 0) ks[NKEY] = NNZ_C;
}

// ---------------------------------------------------------------------------
// Sort pass 3: direct scatter into key-grouped es (order within a (row,r)
// segment is arbitrary — the downstream sum is order-insensitive).
// payload: x = c | r<<16, y = val bits
// ---------------------------------------------------------------------------
__global__ __launch_bounds__(256) void scatterK_kernel(
        const int* __restrict__ rows,
        const int* __restrict__ cols,
        const float* __restrict__ vals,
        int* __restrict__ cursor,
        uint2* __restrict__ es) {
    int tid = threadIdx.x;
    int base_e = blockIdx.x * EPB;
    int    key[16];
    uint32 pk[16];
    float  vv[16];
#pragma unroll
    for (int it = 0; it < 16; ++it) {
        int e = base_e + it * 256 + tid;
        if (e < NNZ_C) {
            int row = rows[e];
            int col = cols[e];
            int r   = (int)((uint32)col / (uint32)NN);
            int c   = col - r * NN;
            key[it] = row * 16 + r;
            pk[it]  = (uint32)c | ((uint32)r << 16);
            vv[it]  = vals[e];
        } else key[it] = -1;
    }
#pragma unroll
    for (int it = 0; it < 16; ++it) {
        if (key[it] >= 0) {
            int pos = atomicAdd(&cursor[key[it]], 1);
            es[pos] = make_uint2(pk[it], __float_as_uint(vv[it]));
        }
    }
}

// ---------------------------------------------------------------------------
// Zc build, scalarized: one wave per row. Edge stream is (row,r)-grouped with
// r embedded in es.x[19:16]; record control words are wave-uniform ->
// readfirstlane puts control (bounds, r-switch, fold) on the SALU pipe.
// Per edge: 1 coalesced 256B X-row gather + 2 unpack + 1 v_pk_fma_f32 whose
// val operand is broadcast from the payload pair's high word via op_sel
// (no second readfirstlane, no duplicate movs). Modulo-4-unrolled 16-edge
// body: record sets A,B,C,D cycle by naming -> zero rotation movs.
// Fold into 8 comp-weighted accumulators via v_pk_fma_f32 with {c,c} pairs
// broadcast-read from LDS.
// ---------------------------------------------------------------------------
__global__ __launch_bounds__(256) void zc_build_kernel(
        const uint2* __restrict__ es,
        const int* __restrict__ ks,
        const uint32* __restrict__ XD,
        const float* __restrict__ comp,
        uint32* __restrict__ ZD) {
    __shared__ __align__(16) float cl2[256];   // [r*16 + 2b] = {c,c} pairs
    int tid = threadIdx.x;
    if (tid < 128) {
        float c = comp[tid];
        cl2[tid * 2]     = c;
        cl2[tid * 2 + 1] = c;
    }
    __syncthreads();

    const int row  = __builtin_amdgcn_readfirstlane(blockIdx.x * 4 + (tid >> 6));
    const int lane = tid & 63;

    int beg = __builtin_amdgcn_readfirstlane(ks[row * 16]);
    int end = __builtin_amdgcn_readfirstlane(ks[row * 16 + 16]); // ==NNZ for last row

    float2v zb[8];
#pragma unroll
    for (int b = 0; b < 8; ++b) zb[b] = (float2v){0.f, 0.f};

    if (beg < end) {
        const int endm1 = end - 1;
        float2v a = (float2v){0.f, 0.f};

#define LREC(C, R, P, IDX)                                                 \
        { int i_ = (IDX) < endm1 ? (IDX) : endm1;                          \
          P = *(const uint2v*)(es + i_);                                   \
          uint32 px_ = __builtin_amdgcn_readfirstlane(P.x);                \
          C = (int)(px_ & 0xffffu); R = (int)(px_ >> 16); }

#define LX(X, C)  X = XD[((size_t)(C) << 6) + lane];

#define FOLD                                                               \
        { const float2v* cp_ = (const float2v*)(cl2 + r_cur * 16);         \
          _Pragma("unroll")                                                \
          for (int b_ = 0; b_ < 8; ++b_) {                                 \
              float2v c_ = cp_[b_];                                        \
              asm("v_pk_fma_f32 %0, %1, %2, %0"                            \
                  : "+v"(zb[b_]) : "v"(c_), "v"(a));                       \
          } }

// a.lo += xf.lo * P.w1 ; a.hi += xf.hi * P.w1  (val broadcast via op_sel)
#define CONS(R, P, X, K)                                                   \
        if (e + (K) < end) {                                               \
            if ((R) != r_cur) {                                            \
                FOLD                                                       \
                a = (float2v){0.f, 0.f};                                   \
                r_cur = (R);                                               \
            }                                                              \
            float2v xf_;                                                   \
            xf_.x = __uint_as_float((X) << 16);                            \
            xf_.y = __uint_as_float((X) & 0xffff0000u);                    \
            asm("v_pk_fma_f32 %0, %1, %2, %0 op_sel:[0,1,0] op_sel_hi:[1,1,1]" \
                : "+v"(a) : "v"(xf_), "v"(P));                             \
        }

        int    cA0, cA1, cA2, cA3, rA0, rA1, rA2, rA3;
        int    cB0, cB1, cB2, cB3, rB0, rB1, rB2, rB3;
        int    cC0, cC1, cC2, cC3, rC0, rC1, rC2, rC3;
        int    cD0, cD1, cD2, cD3, rD0, rD1, rD2, rD3;
        uint2v pA0, pA1, pA2, pA3, pB0, pB1, pB2, pB3;
        uint2v pC0, pC1, pC2, pC3, pD0, pD1, pD2, pD3;
        uint32 xA0, xA1, xA2, xA3, xB0, xB1, xB2, xB3;
        uint32 xC0, xC1, xC2, xC3, xD0, xD1, xD2, xD3;

        LREC(cA0, rA0, pA0, beg + 0)
        LREC(cA1, rA1, pA1, beg + 1)
        LREC(cA2, rA2, pA2, beg + 2)
        LREC(cA3, rA3, pA3, beg + 3)
        LREC(cB0, rB0, pB0, beg + 4)
        LREC(cB1, rB1, pB1, beg + 5)
        LREC(cB2, rB2, pB2, beg + 6)
        LREC(cB3, rB3, pB3, beg + 7)
        LX(xA0, cA0) LX(xA1, cA1) LX(xA2, cA2) LX(xA3, cA3)

        int r_cur = rA0;

        for (int e = beg; e < end; e += 16) {
            // ---- half 1: consume A,B ; load records C,D and x for B,C ----
            LX(xB0, cB0) LX(xB1, cB1) LX(xB2, cB2) LX(xB3, cB3)
            LREC(cC0, rC0, pC0, e + 8)
            LREC(cC1, rC1, pC1, e + 9)
            LREC(cC2, rC2, pC2, e + 10)
            LREC(cC3, rC3, pC3, e + 11)

            CONS(rA0, pA0, xA0, 0)
            CONS(rA1, pA1, xA1, 1)
            CONS(rA2, pA2, xA2, 2)
            CONS(rA3, pA3, xA3, 3)

            LX(xC0, cC0) LX(xC1, cC1) LX(xC2, cC2) LX(xC3, cC3)
            LREC(cD0, rD0, pD0, e + 12)
            LREC(cD1, rD1, pD1, e + 13)
            LREC(cD2, rD2, pD2, e + 14)
            LREC(cD3, rD3, pD3, e + 15)

            CONS(rB0, pB0, xB0, 4)
            CONS(rB1, pB1, xB1, 5)
            CONS(rB2, pB2, xB2, 6)
            CONS(rB3, pB3, xB3, 7)

            // ---- half 2: consume C,D ; reload A,B for e+16 (no movs) ----
            LX(xD0, cD0) LX(xD1, cD1) LX(xD2, cD2) LX(xD3, cD3)
            LREC(cA0, rA0, pA0, e + 16)
            LREC(cA1, rA1, pA1, e + 17)
            LREC(cA2, rA2, pA2, e + 18)
            LREC(cA3, rA3, pA3, e + 19)

            CONS(rC0, pC0, xC0, 8)
            CONS(rC1, pC1, xC1, 9)
            CONS(rC2, pC2, xC2, 10)
            CONS(rC3, pC3, xC3, 11)

            LX(xA0, cA0) LX(xA1, cA1) LX(xA2, cA2) LX(xA3, cA3)
            LREC(cB0, rB0, pB0, e + 20)
            LREC(cB1, rB1, pB1, e + 21)
            LREC(cB2, rB2, pB2, e + 22)
            LREC(cB3, rB3, pB3, e + 23)

            CONS(rD0, pD0, xD0, 12)
            CONS(rD1, pD1, xD1, 13)
            CONS(rD2, pD2, xD2, 14)
            CONS(rD3, pD3, xD3, 15)
        }
        FOLD   // final run
#undef CONS
#undef FOLD
#undef LX
#undef LREC
    }

#pragma unroll
    for (int b = 0; b < 8; ++b)
        ZD[(size_t)row * 512 + b * 64 + lane] = pack_bf16(zb[b].x, zb[b].y);
}

// ---------------------------------------------------------------------------
// Dense GEMM (m97-style): out[n, jout] = sum_k Zc[n, k] * Bst[jout, k].
// Block = 128 rows x 128 jout, 256 thr (4 waves, 2x2), K=1024 in 16 BK=64
// slabs. A+B staged via global_load_lds(16B); fragment reads ds_read_b128
// with XOR chunk-swizzle p = row*8 + (kc ^ (row&7)) -> 2-way banks (free).
// ---------------------------------------------------------------------------
__global__ __launch_bounds__(256) void gemm_out_kernel(
        const ushort16* __restrict__ Zc,
        const ushort16* __restrict__ Bst,
        float* __restrict__ out) {
    __shared__ __align__(16) char lds[32768];
    char* Al = lds;               // 16 KB: A slab 128 rows x 64 k
    char* Bl = lds + 16384;       // 16 KB: B slab 128 jout x 64 k

    const int tid  = threadIdx.x;
    const int wave = tid >> 6;
    const int lane = tid & 63;
    const int m    = lane & 15;
    const int half = lane >> 4;
    const int wr   = wave >> 1;          // row half of block
    const int wc   = wave & 1;           // col half of block
    const size_t arow0 = (size_t)blockIdx.x * 128;

    floatx4 acc[16] = {};

    for (int slab = 0; slab < 16; ++slab) {
        const int k0 = slab * 64;
        // stage: physical chunk s holds (row = s>>3, kc = (s&7)^(row&7))
#pragma unroll
        for (int rd = 0; rd < 4; ++rd) {
            int s   = rd * 256 + wave * 64 + lane;
            int row = s >> 3;
            int kc  = (s & 7) ^ (row & 7);
            size_t ldsoff = (size_t)(rd * 256 + wave * 64) * 16;
            gload16(Zc  + ((arow0 + row) << 10) + k0 + (kc << 3), Al + ldsoff);
            gload16(Bst + ((size_t)row << 10)   + k0 + (kc << 3), Bl + ldsoff);
        }
        __syncthreads();

#pragma unroll
        for (int c = 0; c < 2; ++c) {
            short8 a[4], bfr[4];
#pragma unroll
            for (int mt = 0; mt < 4; ++mt) {
                int row = wr * 64 + mt * 16 + m;
                int p   = row * 8 + ((c * 4 + half) ^ (m & 7));
                a[mt] = *(const short8*)(Al + p * 16);
            }
#pragma unroll
            for (int nt = 0; nt < 4; ++nt) {
                int rowb = wc * 64 + nt * 16 + m;
                int p    = rowb * 8 + ((c * 4 + half) ^ (m & 7));
                bfr[nt] = *(const short8*)(Bl + p * 16);
            }
#pragma unroll
            for (int mt = 0; mt < 4; ++mt)
#pragma unroll
                for (int nt = 0; nt < 4; ++nt)
                    acc[mt * 4 + nt] = __builtin_amdgcn_mfma_f32_16x16x32_bf16(
                        a[mt], bfr[nt], acc[mt * 4 + nt], 0, 0, 0);
        }
        __syncthreads();
    }

    // epilogue: C/D layout col = m (jout tile), row = half*4 + reg
#pragma unroll
    for (int mt = 0; mt < 4; ++mt) {
#pragma unroll
        for (int reg = 0; reg < 4; ++reg) {
            int grow = (int)arow0 + wr * 64 + mt * 16 + half * 4 + reg;
            if (grow < NN) {
#pragma unroll
                for (int nt = 0; nt < 4; ++nt)
                    out[(size_t)grow * DOUT + wc * 64 + nt * 16 + m] =
                        acc[mt * 4 + nt][reg];
            }
        }
    }
}

// ---------------------------------------------------------------------------
extern "C" void kernel_launch(void* const* d_in, const int* in_sizes, int n_in,
                              void* d_out, int out_size, void* d_ws, size_t ws_size,
                              hipStream_t stream) {
    const float* X      = (const float*)d_in[0];
    const int*   A_rows = (const int*)d_in[1];
    const int*   A_cols = (const int*)d_in[2];
    const float* A_vals = (const float*)d_in[3];
    const float* basis  = (const float*)d_in[4];
    const float* comp   = (const float*)d_in[5];
    float* out = (float*)d_out;

    // workspace layout (peak ~134.7 MB, under the proven 218.7 MB budget)
    char* ws = (char*)d_ws;
    ushort16* Bst    = (ushort16*)(ws + 0);            // 256 KB
    uint32*   XD     = (uint32*)(ws + 262144);         // 12.8 MB -> ends 13,062,144
    int*      ks     = (int*)(ws + 13062400);          // 800001 ints -> ends 16,262,404
    int*      cursor = (int*)(ws + 16262656);          // 800000 ints (hist counts, then cursors)
    int*      bsum   = (int*)(ws + 19462912);          // 256 ints
    uint2*    es     = (uint2*)(ws + 19464192);        // 12.8 MB -> ends 32,264,192
    ushort16* Zc     = (ushort16*)(ws + 32264448);     // 102.4 MB -> ends 134,664,448
    uint32*   ZD     = (uint32*)Zc;

    hipMemsetAsync(cursor, 0, NKEY * sizeof(int), stream);

    build_bst_kernel<<<512, 256, 0, stream>>>(basis, Bst);
    cvt_x_kernel<<<12500, 256, 0, stream>>>(X, XD);

    histK_kernel<<<NBLK_E, 256, 0, stream>>>(A_rows, A_cols, cursor);
    scan1_kernel<<<NBLK_K, 256, 0, stream>>>(cursor, ks, bsum);
    scan2_kernel<<<NBLK_K, 256, 0, stream>>>(bsum, ks, cursor);
    scatterK_kernel<<<NBLK_E, 256, 0, stream>>>(A_rows, A_cols, A_vals,
                                                cursor, es);

    zc_build_kernel<<<12500, 256, 0, stream>>>(es, ks, XD, comp, ZD);

    gemm_out_kernel<<<(NN + 127) / 128, 256, 0, stream>>>(Zc, Bst, out);
}

// Round 3
// 256.036 us; speedup vs baseline: 1.5400x; 1.5400x over previous
//
#include <hip/hip_runtime.h>

typedef unsigned int   uint32;
typedef unsigned short ushort16;

#define NN       50000
#define RR       16
#define BB       8
#define DIN      128
#define DOUT     128
#define K2       1024          // B*DIN (basis-combined K)
#define NNZ_C    1600000
#define NBUCK    782           // row>>6 buckets (64 rows each)
#define NSUB     1024          // sub-keys per bucket: (row&63)*16 + r
#define EPB      4096          // edges per block in sort passes
#define NBLK_E   391           // ceil(NNZ/EPB)

typedef short  short8  __attribute__((ext_vector_type(8)));
typedef float  floatx4 __attribute__((ext_vector_type(4)));
typedef float  float2v __attribute__((ext_vector_type(2)));
typedef uint32 uint2v  __attribute__((ext_vector_type(2)));

__device__ __forceinline__ ushort16 f2bf(float f) {
    uint32 u = __float_as_uint(f);
    u += 0x7fffu + ((u >> 16) & 1u);   // RNE
    return (ushort16)(u >> 16);
}

// pack two f32 -> (bf16(b)<<16)|bf16(a), round-half-up
__device__ __forceinline__ uint32 pack_bf16(float a, float b) {
    uint32 ua = __float_as_uint(a) + 0x8000u;
    uint32 ub = __float_as_uint(b) + 0x8000u;
    return __builtin_amdgcn_perm(ub, ua, 0x07060302);
}

// async global->LDS, 16B per lane; LDS dest = uniform base + lane*16
__device__ __forceinline__ void gload16(const void* g, void* l) {
    __builtin_amdgcn_global_load_lds(
        (const __attribute__((address_space(1))) uint32*)g,
        (__attribute__((address_space(3))) uint32*)l, 16, 0, 0);
}

// ---------------------------------------------------------------------------
// Bst[jout][b*128+jin] = basis[b][jin][jout]   (bf16 transpose-cast)
// ---------------------------------------------------------------------------
__global__ void build_bst_kernel(const float* __restrict__ basis,
                                 ushort16* __restrict__ Bst) {
    int idx  = blockIdx.x * 256 + threadIdx.x;   // 128*1024 = 131072
    int jout = idx >> 10;
    int bk   = idx & 1023;           // b*128 + jin
    Bst[idx] = f2bf(basis[(size_t)bk * DOUT + jout]);
}

// ---------------------------------------------------------------------------
// X (f32, N x 128) -> XD (bf16 packed dwords, N x 64 dwords)
// ---------------------------------------------------------------------------
__global__ void cvt_x_kernel(const float* __restrict__ X,
                             uint32* __restrict__ XD) {
    int d = blockIdx.x * 256 + threadIdx.x;      // 3,200,000 dwords
    float2 f = *(const float2*)(X + (size_t)d * 2);
    XD[d] = pack_bf16(f.x, f.y);
}

// ---------------------------------------------------------------------------
// Sort pass 1: global bucket histogram (LDS-aggregated, bucket = row>>6)
// ---------------------------------------------------------------------------
__global__ void histB_kernel(const int* __restrict__ rows,
                             int* __restrict__ counts) {
    __shared__ int h[NBUCK];
    int tid = threadIdx.x;
    for (int j = tid; j < NBUCK; j += 256) h[j] = 0;
    __syncthreads();
    int base_e = blockIdx.x * EPB;
#pragma unroll
    for (int it = 0; it < 16; ++it) {
        int e = base_e + it * 256 + tid;
        if (e < NNZ_C) atomicAdd(&h[rows[e] >> 6], 1);
    }
    __syncthreads();
    for (int j = tid; j < NBUCK; j += 256)
        if (h[j]) atomicAdd(&counts[j], h[j]);
}

// ---------------------------------------------------------------------------
// Sort pass 2: scan 782 bucket counts (single block, 4/thread); init cursors
// ---------------------------------------------------------------------------
__global__ void scanB_kernel(const int* __restrict__ counts,
                             int* __restrict__ bucket_start,
                             int* __restrict__ cursor) {
    __shared__ int tmp[256];
    int tid = threadIdx.x;
    int v[4];
    int run = 0;
#pragma unroll
    for (int k = 0; k < 4; ++k) {
        int j = tid * 4 + k;
        int c = (j < NBUCK) ? counts[j] : 0;
        v[k] = run;
        run += c;
    }
    tmp[tid] = run;
    __syncthreads();
#pragma unroll
    for (int off = 1; off < 256; off <<= 1) {
        int t = (tid >= off) ? tmp[tid - off] : 0;
        __syncthreads();
        tmp[tid] += t;
        __syncthreads();
    }
    int excl = tmp[tid] - run;
#pragma unroll
    for (int k = 0; k < 4; ++k) {
        int j = tid * 4 + k;
        if (j < NBUCK) {
            int s = excl + v[k];
            bucket_start[j] = s;
            cursor[j] = s;
        }
    }
    if (tid == 255) bucket_start[NBUCK] = tmp[255];   // == NNZ
}

// ---------------------------------------------------------------------------
// Sort pass 3: per-block range reservation + scatter into bucket-grouped es2.
// payload x = c(16b) | kl(10b)<<16, kl = (row&63)*16 + r ; y = val bits
// ---------------------------------------------------------------------------
__global__ __launch_bounds__(256) void scatterB_kernel(
        const int* __restrict__ rows,
        const int* __restrict__ cols,
        const float* __restrict__ vals,
        int* __restrict__ cursor,
        uint2* __restrict__ es2) {
    __shared__ int h[NBUCK], gbase[NBUCK], lcur[NBUCK];
    int tid = threadIdx.x;
    for (int j = tid; j < NBUCK; j += 256) { h[j] = 0; lcur[j] = 0; }
    __syncthreads();

    int    rowv[16];
    uint32 pkx[16];
    float  vv[16];
    int base_e = blockIdx.x * EPB;
#pragma unroll
    for (int it = 0; it < 16; ++it) {
        int e = base_e + it * 256 + tid;
        if (e < NNZ_C) {
            int row = rows[e];
            int col = cols[e];
            int r   = (int)((uint32)col / (uint32)NN);
            int c   = col - r * NN;
            rowv[it] = row;
            pkx[it]  = (uint32)c | ((uint32)(((row & 63) << 4) | r) << 16);
            vv[it]   = vals[e];
            atomicAdd(&h[row >> 6], 1);
        } else rowv[it] = -1;
    }
    __syncthreads();
    for (int j = tid; j < NBUCK; j += 256)
        if (h[j] > 0) gbase[j] = atomicAdd(&cursor[j], h[j]);
    __syncthreads();
#pragma unroll
    for (int it = 0; it < 16; ++it) {
        if (rowv[it] >= 0) {
            int b   = rowv[it] >> 6;
            int pos = gbase[b] + atomicAdd(&lcur[b], 1);
            es2[pos] = make_uint2(pkx[it], __float_as_uint(vv[it]));
        }
    }
}

// ---------------------------------------------------------------------------
// Sort pass 4: one block per bucket (782 blocks, ~3/CU) — LDS counting-sort
// by sub-key kl = (row&63)*16 + r ; writes final es (x = c | r<<16, y = val)
// and ks[b*1024 + kl] == ks[row*16 + r] = global segment start.
// ---------------------------------------------------------------------------
__global__ __launch_bounds__(256) void sortB_kernel(
        const uint2* __restrict__ es2,
        const int* __restrict__ bucket_start,
        uint2* __restrict__ es,
        int* __restrict__ ks) {
    __shared__ int h[NSUB];
    __shared__ int cur[NSUB];
    __shared__ int tmp[256];
    int b    = blockIdx.x;
    int tid  = threadIdx.x;
    int base = bucket_start[b];
    int n    = bucket_start[b + 1] - base;

#pragma unroll
    for (int j = 0; j < 4; ++j) h[j * 256 + tid] = 0;
    __syncthreads();
    for (int i = tid; i < n; i += 256) {
        uint2 p = es2[base + i];
        atomicAdd(&h[(p.x >> 16) & 1023u], 1);
    }
    __syncthreads();

    // block-wide exclusive scan over 1024 counters (4/thread)
    int run = 0;
    int loc[4];
#pragma unroll
    for (int j = 0; j < 4; ++j) {
        int c = h[tid * 4 + j];
        loc[j] = run;
        run += c;
    }
    tmp[tid] = run;
    __syncthreads();
#pragma unroll
    for (int off = 1; off < 256; off <<= 1) {
        int t = (tid >= off) ? tmp[tid - off] : 0;
        __syncthreads();
        tmp[tid] += t;
        __syncthreads();
    }
    int excl_t = tmp[tid] - run;
#pragma unroll
    for (int j = 0; j < 4; ++j) {
        int idx = tid * 4 + j;
        int st  = loc[j] + excl_t;
        cur[idx] = st;
        ks[b * NSUB + idx] = base + st;
    }
    __syncthreads();

    for (int i = tid; i < n; i += 256) {
        uint2 p  = es2[base + i];
        int   kl = (p.x >> 16) & 1023u;
        int  pos = atomicAdd(&cur[kl], 1);
        // final payload keeps r (= kl&15) in bits 16..19
        es[base + pos] = make_uint2((p.x & 0xffffu) | ((uint32)(kl & 15) << 16),
                                    p.y);
    }
}

// ---------------------------------------------------------------------------
// Zc build, scalarized: one wave per row. Edge stream is (row,r)-grouped with
// r embedded in es.x[19:16]; record control words are wave-uniform ->
// readfirstlane puts control (bounds, r-switch, fold) on the SALU pipe.
// Per edge: 1 coalesced 256B X-row gather + 2 unpack + 1 v_pk_fma_f32 whose
// val operand is broadcast from the payload pair's high word via op_sel
// (no second readfirstlane, no duplicate movs). Modulo-4-unrolled 16-edge
// body: record sets A,B,C,D cycle by naming -> zero rotation movs.
// Fold into 8 comp-weighted accumulators via v_pk_fma_f32 with {c,c} pairs
// broadcast-read from LDS.
// ---------------------------------------------------------------------------
__global__ __launch_bounds__(256) void zc_build_kernel(
        const uint2* __restrict__ es,
        const int* __restrict__ ks,
        const uint32* __restrict__ XD,
        const float* __restrict__ comp,
        uint32* __restrict__ ZD) {
    __shared__ __align__(16) float cl2[256];   // [r*16 + 2b] = {c,c} pairs
    int tid = threadIdx.x;
    if (tid < 128) {
        float c = comp[tid];
        cl2[tid * 2]     = c;
        cl2[tid * 2 + 1] = c;
    }
    __syncthreads();

    const int row  = __builtin_amdgcn_readfirstlane(blockIdx.x * 4 + (tid >> 6));
    const int lane = tid & 63;

    int beg = __builtin_amdgcn_readfirstlane(ks[row * 16]);
    int end = __builtin_amdgcn_readfirstlane(ks[row * 16 + 16]); // ==NNZ for last row

    float2v zb[8];
#pragma unroll
    for (int b = 0; b < 8; ++b) zb[b] = (float2v){0.f, 0.f};

    if (beg < end) {
        const int endm1 = end - 1;
        float2v a = (float2v){0.f, 0.f};

#define LREC(C, R, P, IDX)                                                 \
        { int i_ = (IDX) < endm1 ? (IDX) : endm1;                          \
          P = *(const uint2v*)(es + i_);                                   \
          uint32 px_ = __builtin_amdgcn_readfirstlane(P.x);                \
          C = (int)(px_ & 0xffffu); R = (int)(px_ >> 16); }

#define LX(X, C)  X = XD[((size_t)(C) << 6) + lane];

#define FOLD                                                               \
        { const float2v* cp_ = (const float2v*)(cl2 + r_cur * 16);         \
          _Pragma("unroll")                                                \
          for (int b_ = 0; b_ < 8; ++b_) {                                 \
              float2v c_ = cp_[b_];                                        \
              asm("v_pk_fma_f32 %0, %1, %2, %0"                            \
                  : "+v"(zb[b_]) : "v"(c_), "v"(a));                       \
          } }

// a.lo += xf.lo * P.w1 ; a.hi += xf.hi * P.w1  (val broadcast via op_sel)
#define CONS(R, P, X, K)                                                   \
        if (e + (K) < end) {                                               \
            if ((R) != r_cur) {                                            \
                FOLD                                                       \
                a = (float2v){0.f, 0.f};                                   \
                r_cur = (R);                                               \
            }                                                              \
            float2v xf_;                                                   \
            xf_.x = __uint_as_float((X) << 16);                            \
            xf_.y = __uint_as_float((X) & 0xffff0000u);                    \
            asm("v_pk_fma_f32 %0, %1, %2, %0 op_sel:[0,1,0] op_sel_hi:[1,1,1]" \
                : "+v"(a) : "v"(xf_), "v"(P));                             \
        }

        int    cA0, cA1, cA2, cA3, rA0, rA1, rA2, rA3;
        int    cB0, cB1, cB2, cB3, rB0, rB1, rB2, rB3;
        int    cC0, cC1, cC2, cC3, rC0, rC1, rC2, rC3;
        int    cD0, cD1, cD2, cD3, rD0, rD1, rD2, rD3;
        uint2v pA0, pA1, pA2, pA3, pB0, pB1, pB2, pB3;
        uint2v pC0, pC1, pC2, pC3, pD0, pD1, pD2, pD3;
        uint32 xA0, xA1, xA2, xA3, xB0, xB1, xB2, xB3;
        uint32 xC0, xC1, xC2, xC3, xD0, xD1, xD2, xD3;

        LREC(cA0, rA0, pA0, beg + 0)
        LREC(cA1, rA1, pA1, beg + 1)
        LREC(cA2, rA2, pA2, beg + 2)
        LREC(cA3, rA3, pA3, beg + 3)
        LREC(cB0, rB0, pB0, beg + 4)
        LREC(cB1, rB1, pB1, beg + 5)
        LREC(cB2, rB2, pB2, beg + 6)
        LREC(cB3, rB3, pB3, beg + 7)
        LX(xA0, cA0) LX(xA1, cA1) LX(xA2, cA2) LX(xA3, cA3)

        int r_cur = rA0;

        for (int e = beg; e < end; e += 16) {
            // ---- half 1: consume A,B ; load records C,D and x for B,C ----
            LX(xB0, cB0) LX(xB1, cB1) LX(xB2, cB2) LX(xB3, cB3)
            LREC(cC0, rC0, pC0, e + 8)
            LREC(cC1, rC1, pC1, e + 9)
            LREC(cC2, rC2, pC2, e + 10)
            LREC(cC3, rC3, pC3, e + 11)

            CONS(rA0, pA0, xA0, 0)
            CONS(rA1, pA1, xA1, 1)
            CONS(rA2, pA2, xA2, 2)
            CONS(rA3, pA3, xA3, 3)

            LX(xC0, cC0) LX(xC1, cC1) LX(xC2, cC2) LX(xC3, cC3)
            LREC(cD0, rD0, pD0, e + 12)
            LREC(cD1, rD1, pD1, e + 13)
            LREC(cD2, rD2, pD2, e + 14)
            LREC(cD3, rD3, pD3, e + 15)

            CONS(rB0, pB0, xB0, 4)
            CONS(rB1, pB1, xB1, 5)
            CONS(rB2, pB2, xB2, 6)
            CONS(rB3, pB3, xB3, 7)

            // ---- half 2: consume C,D ; reload A,B for e+16 (no movs) ----
            LX(xD0, cD0) LX(xD1, cD1) LX(xD2, cD2) LX(xD3, cD3)
            LREC(cA0, rA0, pA0, e + 16)
            LREC(cA1, rA1, pA1, e + 17)
            LREC(cA2, rA2, pA2, e + 18)
            LREC(cA3, rA3, pA3, e + 19)

            CONS(rC0, pC0, xC0, 8)
            CONS(rC1, pC1, xC1, 9)
            CONS(rC2, pC2, xC2, 10)
            CONS(rC3, pC3, xC3, 11)

            LX(xA0, cA0) LX(xA1, cA1) LX(xA2, cA2) LX(xA3, cA3)
            LREC(cB0, rB0, pB0, e + 20)
            LREC(cB1, rB1, pB1, e + 21)
            LREC(cB2, rB2, pB2, e + 22)
            LREC(cB3, rB3, pB3, e + 23)

            CONS(rD0, pD0, xD0, 12)
            CONS(rD1, pD1, xD1, 13)
            CONS(rD2, pD2, xD2, 14)
            CONS(rD3, pD3, xD3, 15)
        }
        FOLD   // final run
#undef CONS
#undef FOLD
#undef LX
#undef LREC
    }

#pragma unroll
    for (int b = 0; b < 8; ++b)
        ZD[(size_t)row * 512 + b * 64 + lane] = pack_bf16(zb[b].x, zb[b].y);
}

// ---------------------------------------------------------------------------
// Dense GEMM (m97-style): out[n, jout] = sum_k Zc[n, k] * Bst[jout, k].
// Block = 128 rows x 128 jout, 256 thr (4 waves, 2x2), K=1024 in 16 BK=64
// slabs. A+B staged via global_load_lds(16B); fragment reads ds_read_b128
// with XOR chunk-swizzle p = row*8 + (kc ^ (row&7)) -> 2-way banks (free).
// ---------------------------------------------------------------------------
__global__ __launch_bounds__(256) void gemm_out_kernel(
        const ushort16* __restrict__ Zc,
        const ushort16* __restrict__ Bst,
        float* __restrict__ out) {
    __shared__ __align__(16) char lds[32768];
    char* Al = lds;               // 16 KB: A slab 128 rows x 64 k
    char* Bl = lds + 16384;       // 16 KB: B slab 128 jout x 64 k

    const int tid  = threadIdx.x;
    const int wave = tid >> 6;
    const int lane = tid & 63;
    const int m    = lane & 15;
    const int half = lane >> 4;
    const int wr   = wave >> 1;          // row half of block
    const int wc   = wave & 1;           // col half of block
    const size_t arow0 = (size_t)blockIdx.x * 128;

    floatx4 acc[16] = {};

    for (int slab = 0; slab < 16; ++slab) {
        const int k0 = slab * 64;
        // stage: physical chunk s holds (row = s>>3, kc = (s&7)^(row&7))
#pragma unroll
        for (int rd = 0; rd < 4; ++rd) {
            int s   = rd * 256 + wave * 64 + lane;
            int row = s >> 3;
            int kc  = (s & 7) ^ (row & 7);
            size_t ldsoff = (size_t)(rd * 256 + wave * 64) * 16;
            gload16(Zc  + ((arow0 + row) << 10) + k0 + (kc << 3), Al + ldsoff);
            gload16(Bst + ((size_t)row << 10)   + k0 + (kc << 3), Bl + ldsoff);
        }
        __syncthreads();

#pragma unroll
        for (int c = 0; c < 2; ++c) {
            short8 a[4], bfr[4];
#pragma unroll
            for (int mt = 0; mt < 4; ++mt) {
                int row = wr * 64 + mt * 16 + m;
                int p   = row * 8 + ((c * 4 + half) ^ (m & 7));
                a[mt] = *(const short8*)(Al + p * 16);
            }
#pragma unroll
            for (int nt = 0; nt < 4; ++nt) {
                int rowb = wc * 64 + nt * 16 + m;
                int p    = rowb * 8 + ((c * 4 + half) ^ (m & 7));
                bfr[nt] = *(const short8*)(Bl + p * 16);
            }
#pragma unroll
            for (int mt = 0; mt < 4; ++mt)
#pragma unroll
                for (int nt = 0; nt < 4; ++nt)
                    acc[mt * 4 + nt] = __builtin_amdgcn_mfma_f32_16x16x32_bf16(
                        a[mt], bfr[nt], acc[mt * 4 + nt], 0, 0, 0);
        }
        __syncthreads();
    }

    // epilogue: C/D layout col = m (jout tile), row = half*4 + reg
#pragma unroll
    for (int mt = 0; mt < 4; ++mt) {
#pragma unroll
        for (int reg = 0; reg < 4; ++reg) {
            int grow = (int)arow0 + wr * 64 + mt * 16 + half * 4 + reg;
            if (grow < NN) {
#pragma unroll
                for (int nt = 0; nt < 4; ++nt)
                    out[(size_t)grow * DOUT + wc * 64 + nt * 16 + m] =
                        acc[mt * 4 + nt][reg];
            }
        }
    }
}

// ---------------------------------------------------------------------------
extern "C" void kernel_launch(void* const* d_in, const int* in_sizes, int n_in,
                              void* d_out, int out_size, void* d_ws, size_t ws_size,
                              hipStream_t stream) {
    const float* X      = (const float*)d_in[0];
    const int*   A_rows = (const int*)d_in[1];
    const int*   A_cols = (const int*)d_in[2];
    const float* A_vals = (const float*)d_in[3];
    const float* basis  = (const float*)d_in[4];
    const float* comp   = (const float*)d_in[5];
    float* out = (float*)d_out;

    // workspace layout (peak ~144.3 MB, under the proven 218.7 MB budget)
    char* ws = (char*)d_ws;
    ushort16* Bst          = (ushort16*)(ws + 0);            // 256 KB
    uint32*   XD           = (uint32*)(ws + 262144);         // 12.8 MB -> ends 13,062,144
    int*      ks           = (int*)(ws + 13062400);          // 800768 ints -> ends 16,265,472
    uint2*    es           = (uint2*)(ws + 16265728);        // 12.8 MB -> ends 29,065,728
    int*      bucket_start = (int*)(ws + 29066240);          // 783 ints
    int*      counts       = (int*)(ws + 29070336);          // 782 ints
    int*      cursor       = (int*)(ws + 29074432);          // 782 ints
    uint2*    es2          = (uint2*)(ws + 29078528);        // 12.8 MB -> ends 41,878,528
    ushort16* Zc           = (ushort16*)(ws + 41878528);     // 102.4 MB -> ends 144,278,528
    uint32*   ZD           = (uint32*)Zc;

    hipMemsetAsync(counts, 0, NBUCK * sizeof(int), stream);

    build_bst_kernel<<<512, 256, 0, stream>>>(basis, Bst);
    cvt_x_kernel<<<12500, 256, 0, stream>>>(X, XD);

    histB_kernel<<<NBLK_E, 256, 0, stream>>>(A_rows, counts);
    scanB_kernel<<<1, 256, 0, stream>>>(counts, bucket_start, cursor);
    scatterB_kernel<<<NBLK_E, 256, 0, stream>>>(A_rows, A_cols, A_vals,
                                                cursor, es2);
    sortB_kernel<<<NBUCK, 256, 0, stream>>>(es2, bucket_start, es, ks);

    zc_build_kernel<<<12500, 256, 0, stream>>>(es, ks, XD, comp, ZD);

    gemm_out_kernel<<<(NN + 127) / 128, 256, 0, stream>>>(Zc, Bst, out);
}